// Round 5
// baseline (327.816 us; speedup 1.0000x reference)
//
#include <hip/hip_runtime.h>
#include <hip/hip_bf16.h>
#include <math.h>

#define N_NODES 50000
#define N_EDGES 800000
#define F_IN    256
#define HEADS   8
#define C1      32
#define F1      256   // HEADS*C1
#define C2      16
#define NEG     0.2f
#define EPSF    1e-16f
#define ELLW    96    // ELL width; max real degree ~45 for this graph, guarded
#define HISTB   3125  // 800000/256
#define INITB   196   // ceil(50000/256)

// GEMM1 B panel: 272 cols = 256 (W1) + 8 (W1@a_src per head) + 8 (W1@a_dst)
#define NCOLS   272
#define KCHALF  (NCOLS * 32)          // halfs per kc chunk = 8704
#define KCBYTES (KCHALF * 2)          // 17408 B

typedef __attribute__((ext_vector_type(8))) _Float16 half8;
typedef __attribute__((ext_vector_type(4))) _Float16 half4_t;
typedef __attribute__((ext_vector_type(4))) float    floatx4;

// ------------- weight prep + ELL cursor init (merged) ----------------------
// blocks 0..255   : W1 col -> Wp
// blocks 256..263 : wtS/wtD cols (fused attention coefs)
// blocks 264..    : cursor[i] = 0 (self-loop handled analytically in agg1/2)
__global__ void k_prep(const float* __restrict__ W1,
                       const float* __restrict__ as1, const float* __restrict__ ad1,
                       _Float16* __restrict__ Wp, int* __restrict__ cursor) {
    int b = blockIdx.x;
    int k = threadIdx.x;   // 0..255
    if (b < 256) {
        int n = b;
        float v = W1[k * 256 + n];
        Wp[(k >> 5) * KCHALF + n * 32 + (k & 31)] = (_Float16)v;
    } else if (b < 264) {
        int hd = b - 256;
        float ws = 0.f, wd = 0.f;
        #pragma unroll
        for (int cc = 0; cc < 32; ++cc) {
            float wv = W1[k * 256 + hd * 32 + cc];
            ws += wv * as1[hd * 32 + cc];
            wd += wv * ad1[hd * 32 + cc];
        }
        Wp[(k >> 5) * KCHALF + (256 + hd) * 32 + (k & 31)] = (_Float16)ws;
        Wp[(k >> 5) * KCHALF + (264 + hd) * 32 + (k & 31)] = (_Float16)wd;
    } else {
        int i = (b - 264) * 256 + k;
        if (i < N_NODES) cursor[i] = 0;
    }
}

// ---------------- ELL scatter: one atomic per edge -------------------------
__global__ void k_scatter(const int* __restrict__ ei, int* __restrict__ cursor,
                          int* __restrict__ ssrc) {
    int i = blockIdx.x * blockDim.x + threadIdx.x;
    if (i >= N_EDGES) return;
    int s = ei[i];
    int d = ei[N_EDGES + i];
    int p = atomicAdd(&cursor[d], 1);
    if (p < ELLW) ssrc[(size_t)d * ELLW + p] = s;
}

// ---------------- layer 1 GEMM via split-fp16 MFMA -------------------------
// [h1 | als | ald] = x @ [W1 | wtS | wtD]. 17 n-tiles of 16.
__global__ __launch_bounds__(256) void k_gemm1(
        const float* __restrict__ x, const _Float16* __restrict__ Wp,
        _Float16* __restrict__ h1h, float* __restrict__ als,
        float* __restrict__ ald) {
    __shared__ _Float16 sW[2][KCHALF];
    int t = threadIdx.x;
    int w = t >> 6, l = t & 63;
    int lm = l & 15, q = l >> 4;
    int row0 = blockIdx.x * 64;
    int arow = row0 + w * 16 + lm;
    int rc = (arow < N_NODES) ? arow : (N_NODES - 1);
    const float* xp = x + (size_t)rc * 256 + q * 8;

    floatx4 acc[17];
    #pragma unroll
    for (int nt = 0; nt < 17; ++nt) acc[nt] = (floatx4){0.f, 0.f, 0.f, 0.f};

    auto stage = [&](int kc, int buf) {
        const float4* g = (const float4*)((const char*)Wp + (size_t)kc * KCBYTES);
        float4* sp = (float4*)&sW[buf][0];
        #pragma unroll
        for (int c = 0; c < 4; ++c) sp[c * 256 + t] = g[c * 256 + t];
        if (t < 64) sp[1024 + t] = g[1024 + t];
    };

    stage(0, 0);
    int buf = 0;
    #pragma unroll 1
    for (int kc = 0; kc < 8; ++kc) {
        __syncthreads();
        if (kc < 7) stage(kc + 1, buf ^ 1);

        float4 xa = *(const float4*)(xp + kc * 32);
        float4 xb = *(const float4*)(xp + kc * 32 + 4);
        float xv[8] = {xa.x, xa.y, xa.z, xa.w, xb.x, xb.y, xb.z, xb.w};
        half8 ah, al;
        #pragma unroll
        for (int j = 0; j < 8; ++j) {
            _Float16 h = (_Float16)xv[j];
            ah[j] = h;
            al[j] = (_Float16)(xv[j] - (float)h);
        }
        const _Float16* sb = &sW[buf][(size_t)lm * 32 + q * 8];
        #pragma unroll
        for (int nt = 0; nt < 17; ++nt) {
            half8 b = *(const half8*)(sb + nt * 512);
            acc[nt] = __builtin_amdgcn_mfma_f32_16x16x32_f16(ah, b, acc[nt], 0, 0, 0);
            acc[nt] = __builtin_amdgcn_mfma_f32_16x16x32_f16(al, b, acc[nt], 0, 0, 0);
        }
        buf ^= 1;
    }

    int rbase = row0 + w * 16 + q * 4;
    #pragma unroll
    for (int r = 0; r < 4; ++r) {
        int row = rbase + r;
        if (row < N_NODES) {
            size_t ro = (size_t)row * 256 + lm;
            #pragma unroll
            for (int nt = 0; nt < 16; ++nt)
                h1h[ro + nt * 16] = (_Float16)acc[nt][r];
            float v = acc[16][r];                  // col 256+lm
            if (lm < 8) als[row * 8 + lm] = v;
            else        ald[row * 8 + (lm - 8)] = v;
        }
    }
}

// ------------- layer 1 aggregation + fused layer-2 GEMV --------------------
// One wave per dst node, ELL list (real edges only; self-loop analytic).
// Main loop: LDS-staged 64-edge chunks, 8-edge inner body (8 gathers in
// flight; pad lanes carry w=0 + clamped src so ncp round-up is safe).
// Epilogue: in-register shuffle-tree GEMV with fp32 W2 loads (L1-hot).
__global__ __launch_bounds__(64, 8) void k_agg1(
        const int* __restrict__ cursor, const int* __restrict__ ssrc,
        const _Float16* __restrict__ h1h, const float* __restrict__ als,
        const float* __restrict__ ald, const float* __restrict__ b1,
        const float* __restrict__ W2, const float* __restrict__ as2,
        const float* __restrict__ ad2,
        _Float16* __restrict__ h2h, float* __restrict__ als2,
        float* __restrict__ ald2) {
    __shared__ int   s_lds[64];
    __shared__ float w_lds[64 * 8];
    int l = threadIdx.x;
    int i = blockIdx.x;
    int h = l >> 3;
    float4 ad0  = *(const float4*)(ald + i * 8);
    float4 ad1v = *(const float4*)(ald + i * 8 + 4);

    // ---- analytic self-loop: src = dst = i ----
    float es = als[i * 8 + h] + ald[i * 8 + h];
    es = (es > 0.f) ? es : NEG * es;
    float wself = __expf(es);
    half4_t hvs = *(const half4_t*)(h1h + (size_t)i * 256 + 4 * l);
    float ax = wself * (float)hvs[0];
    float ay = wself * (float)hvs[1];
    float az = wself * (float)hvs[2];
    float aw = wself * (float)hvs[3];
    float dsum = wself;

    int beg = i * ELLW;
    int end = beg + cursor[i];
    for (int c0 = beg; c0 < end; c0 += 64) {
        int nc = min(64, end - c0);
        __syncthreads();
        int jj = (l < nc) ? l : (nc - 1);
        int s = ssrc[c0 + jj];
        s_lds[l] = s;
        float4 s0 = *(const float4*)(als + s * 8);
        float4 s1 = *(const float4*)(als + s * 8 + 4);
        float e0 = s0.x + ad0.x,  e1 = s0.y + ad0.y;
        float e2 = s0.z + ad0.z,  e3 = s0.w + ad0.w;
        float e4 = s1.x + ad1v.x, e5 = s1.y + ad1v.y;
        float e6 = s1.z + ad1v.z, e7 = s1.w + ad1v.w;
        e0 = (e0 > 0.f) ? e0 : NEG * e0;  e1 = (e1 > 0.f) ? e1 : NEG * e1;
        e2 = (e2 > 0.f) ? e2 : NEG * e2;  e3 = (e3 > 0.f) ? e3 : NEG * e3;
        e4 = (e4 > 0.f) ? e4 : NEG * e4;  e5 = (e5 > 0.f) ? e5 : NEG * e5;
        e6 = (e6 > 0.f) ? e6 : NEG * e6;  e7 = (e7 > 0.f) ? e7 : NEG * e7;
        float m = (l < nc) ? 1.f : 0.f;   // zero weight for pad lanes
        float4 w0 = make_float4(m * __expf(e0), m * __expf(e1),
                                m * __expf(e2), m * __expf(e3));
        float4 w1 = make_float4(m * __expf(e4), m * __expf(e5),
                                m * __expf(e6), m * __expf(e7));
        *(float4*)(w_lds + l * 8)     = w0;
        *(float4*)(w_lds + l * 8 + 4) = w1;
        __syncthreads();
        int ncp = (nc + 7) & ~7;          // pad lanes have w=0, clamped src
        for (int e = 0; e < ncp; e += 8) {
            int4 sa = *(const int4*)(s_lds + e);
            int4 sb = *(const int4*)(s_lds + e + 4);
            float w0a = w_lds[(e + 0) * 8 + h];
            float w1a = w_lds[(e + 1) * 8 + h];
            float w2a = w_lds[(e + 2) * 8 + h];
            float w3a = w_lds[(e + 3) * 8 + h];
            float w4a = w_lds[(e + 4) * 8 + h];
            float w5a = w_lds[(e + 5) * 8 + h];
            float w6a = w_lds[(e + 6) * 8 + h];
            float w7a = w_lds[(e + 7) * 8 + h];
            half4_t v0 = *(const half4_t*)(h1h + (size_t)sa.x * 256 + 4 * l);
            half4_t v1 = *(const half4_t*)(h1h + (size_t)sa.y * 256 + 4 * l);
            half4_t v2 = *(const half4_t*)(h1h + (size_t)sa.z * 256 + 4 * l);
            half4_t v3 = *(const half4_t*)(h1h + (size_t)sa.w * 256 + 4 * l);
            half4_t v4 = *(const half4_t*)(h1h + (size_t)sb.x * 256 + 4 * l);
            half4_t v5 = *(const half4_t*)(h1h + (size_t)sb.y * 256 + 4 * l);
            half4_t v6 = *(const half4_t*)(h1h + (size_t)sb.z * 256 + 4 * l);
            half4_t v7 = *(const half4_t*)(h1h + (size_t)sb.w * 256 + 4 * l);
            ax += w0a * (float)v0[0] + w1a * (float)v1[0]
                + w2a * (float)v2[0] + w3a * (float)v3[0]
                + w4a * (float)v4[0] + w5a * (float)v5[0]
                + w6a * (float)v6[0] + w7a * (float)v7[0];
            ay += w0a * (float)v0[1] + w1a * (float)v1[1]
                + w2a * (float)v2[1] + w3a * (float)v3[1]
                + w4a * (float)v4[1] + w5a * (float)v5[1]
                + w6a * (float)v6[1] + w7a * (float)v7[1];
            az += w0a * (float)v0[2] + w1a * (float)v1[2]
                + w2a * (float)v2[2] + w3a * (float)v3[2]
                + w4a * (float)v4[2] + w5a * (float)v5[2]
                + w6a * (float)v6[2] + w7a * (float)v7[2];
            aw += w0a * (float)v0[3] + w1a * (float)v1[3]
                + w2a * (float)v2[3] + w3a * (float)v3[3]
                + w4a * (float)v4[3] + w5a * (float)v5[3]
                + w6a * (float)v6[3] + w7a * (float)v7[3];
            dsum += w0a + w1a + w2a + w3a + w4a + w5a + w6a + w7a;
        }
    }
    float dn = 1.0f / (dsum + EPSF);
    float4 b4 = *(const float4*)(b1 + 4 * l);
    float vx = ax * dn + b4.x;
    float vy = ay * dn + b4.y;
    float vz = az * dn + b4.z;
    float vw = aw * dn + b4.w;
    vx = (vx > 0.f) ? vx : (__expf(vx) - 1.f);
    vy = (vy > 0.f) ? vy : (__expf(vy) - 1.f);
    vz = (vz > 0.f) ? vz : (__expf(vz) - 1.f);
    vw = (vw > 0.f) ? vw : (__expf(vw) - 1.f);

    // ---- fused layer-2 GEMV: h2[c] = sum_k hpost[k] * W2[k][c] ----
    // Lane l holds hpost[4l..4l+3]; W2 read as fp32 (L1-hot, epilogue-only).
    float p[16];
    #pragma unroll
    for (int c = 0; c < 16; ++c) p[c] = 0.f;
    float v4a[4] = {vx, vy, vz, vw};
    const float4* w2p = (const float4*)(W2 + (size_t)(4 * l) * 16);
    #pragma unroll
    for (int j = 0; j < 4; ++j) {
        float4 c0 = w2p[j * 4 + 0];
        float4 c1 = w2p[j * 4 + 1];
        float4 c2 = w2p[j * 4 + 2];
        float4 c3 = w2p[j * 4 + 3];
        float vj = v4a[j];
        p[0]  += vj * c0.x;  p[1]  += vj * c0.y;
        p[2]  += vj * c0.z;  p[3]  += vj * c0.w;
        p[4]  += vj * c1.x;  p[5]  += vj * c1.y;
        p[6]  += vj * c1.z;  p[7]  += vj * c1.w;
        p[8]  += vj * c2.x;  p[9]  += vj * c2.y;
        p[10] += vj * c2.z;  p[11] += vj * c2.w;
        p[12] += vj * c3.x;  p[13] += vj * c3.y;
        p[14] += vj * c3.z;  p[15] += vj * c3.w;
    }
    // shuffle-tree: after 4 stages lane l holds partial of channel (l&15)
    bool k1 = (l & 1) != 0;
    float q[8];
    #pragma unroll
    for (int j = 0; j < 8; ++j) {
        float a = p[2 * j], b = p[2 * j + 1];
        float mine = k1 ? b : a;
        float send = k1 ? a : b;
        q[j] = mine + __shfl_xor(send, 1, 64);
    }
    bool k2 = (l & 2) != 0;
    float r4[4];
    #pragma unroll
    for (int j = 0; j < 4; ++j) {
        float a = q[2 * j], b = q[2 * j + 1];
        float mine = k2 ? b : a;
        float send = k2 ? a : b;
        r4[j] = mine + __shfl_xor(send, 2, 64);
    }
    bool k4 = (l & 4) != 0;
    float s2a[2];
    #pragma unroll
    for (int j = 0; j < 2; ++j) {
        float a = r4[2 * j], b = r4[2 * j + 1];
        float mine = k4 ? b : a;
        float send = k4 ? a : b;
        s2a[j] = mine + __shfl_xor(send, 4, 64);
    }
    bool k8 = (l & 8) != 0;
    {
        float a = s2a[0], b = s2a[1];
        float mine = k8 ? b : a;
        float send = k8 ? a : b;
        s2a[0] = mine + __shfl_xor(send, 8, 64);
    }
    float sum = s2a[0];
    sum += __shfl_xor(sum, 16, 64);
    sum += __shfl_xor(sum, 32, 64);        // every lane: h2[l&15]
    int c = l & 15;
    float vs = sum * as2[c];
    float vd = sum * ad2[c];
    #pragma unroll
    for (int m = 1; m < 16; m <<= 1) {
        vs += __shfl_xor(vs, m, 64);
        vd += __shfl_xor(vd, m, 64);
    }
    if (l < 16) h2h[(size_t)i * 16 + l] = (_Float16)sum;
    if (l == 0) { als2[i] = vs; ald2[i] = vd; }
}

// ---------------- layer 2 aggregation -> out (shuffle-only, ELL) -----------
// Self-loop analytic; real edges from ELL list.
__global__ __launch_bounds__(256) void k_agg2(
        const int* __restrict__ cursor, const int* __restrict__ ssrc,
        const _Float16* __restrict__ h2h, const float* __restrict__ als2,
        const float* __restrict__ ald2, const float* __restrict__ b2,
        float* __restrict__ out) {
    int t = threadIdx.x;
    int l = t & 63;
    int i = blockIdx.x * 4 + (t >> 6);
    int c = l & 15, es = l >> 4;
    float adi = ald2[i];

    // analytic self-loop
    float vsl = als2[i] + adi;
    vsl = (vsl > 0.f) ? vsl : NEG * vsl;
    float wself = __expf(vsl);
    float acc  = (es == 0) ? wself * (float)h2h[(size_t)i * C2 + c] : 0.f;
    float dsum = (l == 0) ? wself : 0.f;

    int beg = i * ELLW;
    int end = beg + cursor[i];
    for (int c0 = beg; c0 < end; c0 += 64) {
        int nc = min(64, end - c0);
        int s = 0; float wv = 0.f;
        if (l < nc) {
            s = ssrc[c0 + l];
            float v = als2[s] + adi;
            v = (v > 0.f) ? v : NEG * v;
            wv = __expf(v);
            dsum += wv;
        }
        for (int e0 = 0; e0 < nc; e0 += 4) {     // uniform trip count
            int e = e0 + es;
            int ec = (e < nc) ? e : (nc - 1);
            int se = __shfl(s, ec, 64);
            float we = __shfl(wv, ec, 64);
            if (e < nc) acc += we * (float)h2h[(size_t)se * C2 + c];
        }
    }
    #pragma unroll
    for (int m = 1; m < 64; m <<= 1) dsum += __shfl_xor(dsum, m, 64);
    acc += __shfl_xor(acc, 16, 64);
    acc += __shfl_xor(acc, 32, 64);
    if (l < 16) out[i * C2 + l] = acc / (dsum + EPSF) + b2[l];
}

// ---------------------------------------------------------------------------

extern "C" void kernel_launch(void* const* d_in, const int* in_sizes, int n_in,
                              void* d_out, int out_size, void* d_ws, size_t ws_size,
                              hipStream_t stream) {
    const float* x   = (const float*)d_in[0];
    const int*   ei  = (const int*)d_in[1];
    const float* W1  = (const float*)d_in[2];
    const float* as1 = (const float*)d_in[3];
    const float* ad1 = (const float*)d_in[4];
    const float* b1  = (const float*)d_in[5];
    const float* W2  = (const float*)d_in[6];
    const float* as2 = (const float*)d_in[7];
    const float* ad2 = (const float*)d_in[8];
    const float* b2  = (const float*)d_in[9];
    float* out = (float*)d_out;

    char* ws = (char*)d_ws;
    size_t off = 0;
    auto alloc = [&](size_t bytes) {
        off = (off + 255) & ~(size_t)255;
        void* p = ws + off;
        off += bytes;
        return p;
    };
    _Float16* h1h    = (_Float16*)alloc((size_t)N_NODES * F1 * 2);
    _Float16* h2h    = (_Float16*)alloc((size_t)N_NODES * C2 * 2);
    float* als   = (float*)alloc((size_t)N_NODES * HEADS * 4);
    float* ald   = (float*)alloc((size_t)N_NODES * HEADS * 4);
    float* als2  = (float*)alloc((size_t)N_NODES * 4);
    float* ald2  = (float*)alloc((size_t)N_NODES * 4);
    int*   cursor= (int*)alloc((size_t)N_NODES * 4);
    int*   ssrc  = (int*)alloc((size_t)N_NODES * ELLW * 4);
    _Float16* Wp  = (_Float16*)alloc((size_t)8 * KCHALF * 2);
    (void)ws_size; (void)in_sizes; (void)n_in; (void)out_size;

    k_prep<<<264 + INITB, 256, 0, stream>>>(W1, as1, ad1, Wp, cursor);
    k_scatter<<<HISTB, 256, 0, stream>>>(ei, cursor, ssrc);
    k_gemm1<<<(N_NODES + 63) / 64, 256, 0, stream>>>(x, Wp, h1h, als, ald);
    k_agg1<<<N_NODES, 64, 0, stream>>>(cursor, ssrc, h1h, als, ald, b1,
                                       W2, as2, ad2, h2h, als2, ald2);
    k_agg2<<<N_NODES / 4, 256, 0, stream>>>(cursor, ssrc, h2h, als2, ald2, b2, out);
}

// Round 6
// 319.399 us; speedup vs baseline: 1.0264x; 1.0264x over previous
//
#include <hip/hip_runtime.h>
#include <hip/hip_bf16.h>
#include <math.h>

#define N_NODES 50000
#define N_EDGES 800000
#define F_IN    256
#define HEADS   8
#define C1      32
#define F1      256   // HEADS*C1
#define C2      16
#define NEG     0.2f
#define EPSF    1e-16f
#define ELLW    96    // ELL width; max real degree ~45 for this graph, guarded
#define HISTB   3125  // 800000/256
#define INITB   196   // ceil(50000/256)
#define GEMMB   782   // ceil(50000/64)

// GEMM1 B panel: 272 cols = 256 (W1) + 8 (W1@a_src per head) + 8 (W1@a_dst)
#define NCOLS   272
#define KCHALF  (NCOLS * 32)          // halfs per kc chunk = 8704
#define KCBYTES (KCHALF * 2)          // 17408 B

typedef __attribute__((ext_vector_type(8))) _Float16 half8;
typedef __attribute__((ext_vector_type(4))) _Float16 half4_t;
typedef __attribute__((ext_vector_type(4))) float    floatx4;

// ------------- weight prep + ELL cursor init (merged) ----------------------
// blocks 0..255   : W1 col -> Wp
// blocks 256..263 : wtS/wtD cols (fused attention coefs)
// blocks 264..    : cursor[i] = 0 (self-loop handled analytically in agg1/2)
__global__ void k_prep(const float* __restrict__ W1,
                       const float* __restrict__ as1, const float* __restrict__ ad1,
                       _Float16* __restrict__ Wp, int* __restrict__ cursor) {
    int b = blockIdx.x;
    int k = threadIdx.x;   // 0..255
    if (b < 256) {
        int n = b;
        float v = W1[k * 256 + n];
        Wp[(k >> 5) * KCHALF + n * 32 + (k & 31)] = (_Float16)v;
    } else if (b < 264) {
        int hd = b - 256;
        float ws = 0.f, wd = 0.f;
        #pragma unroll
        for (int cc = 0; cc < 32; ++cc) {
            float wv = W1[k * 256 + hd * 32 + cc];
            ws += wv * as1[hd * 32 + cc];
            wd += wv * ad1[hd * 32 + cc];
        }
        Wp[(k >> 5) * KCHALF + (256 + hd) * 32 + (k & 31)] = (_Float16)ws;
        Wp[(k >> 5) * KCHALF + (264 + hd) * 32 + (k & 31)] = (_Float16)wd;
    } else {
        int i = (b - 264) * 256 + k;
        if (i < N_NODES) cursor[i] = 0;
    }
}

// -------- layer 1 GEMM via split-fp16 MFMA + ELL scatter (merged grid) -----
// Blocks 0..GEMMB-1: [h1 | als | ald] = x @ [W1 | wtS | wtD], 17 n-tiles.
// Blocks GEMMB.. : edge scatter into ELL (depends only on k_prep, like GEMM;
// no ordering needed between the two halves -> safe to share one dispatch).
__global__ __launch_bounds__(256) void k_gemm1(
        const float* __restrict__ x, const _Float16* __restrict__ Wp,
        _Float16* __restrict__ h1h, float* __restrict__ als,
        float* __restrict__ ald,
        const int* __restrict__ ei, int* __restrict__ cursor,
        int* __restrict__ ssrc) {
    __shared__ _Float16 sW[2][KCHALF];
    if (blockIdx.x >= GEMMB) {
        int i = (blockIdx.x - GEMMB) * 256 + threadIdx.x;
        if (i < N_EDGES) {
            int s = ei[i];
            int d = ei[N_EDGES + i];
            int p = atomicAdd(&cursor[d], 1);
            if (p < ELLW) ssrc[(size_t)d * ELLW + p] = s;
        }
        return;
    }
    int t = threadIdx.x;
    int w = t >> 6, l = t & 63;
    int lm = l & 15, q = l >> 4;
    int row0 = blockIdx.x * 64;
    int arow = row0 + w * 16 + lm;
    int rc = (arow < N_NODES) ? arow : (N_NODES - 1);
    const float* xp = x + (size_t)rc * 256 + q * 8;

    floatx4 acc[17];
    #pragma unroll
    for (int nt = 0; nt < 17; ++nt) acc[nt] = (floatx4){0.f, 0.f, 0.f, 0.f};

    auto stage = [&](int kc, int buf) {
        const float4* g = (const float4*)((const char*)Wp + (size_t)kc * KCBYTES);
        float4* sp = (float4*)&sW[buf][0];
        #pragma unroll
        for (int c = 0; c < 4; ++c) sp[c * 256 + t] = g[c * 256 + t];
        if (t < 64) sp[1024 + t] = g[1024 + t];
    };

    stage(0, 0);
    int buf = 0;
    #pragma unroll 1
    for (int kc = 0; kc < 8; ++kc) {
        __syncthreads();
        if (kc < 7) stage(kc + 1, buf ^ 1);

        float4 xa = *(const float4*)(xp + kc * 32);
        float4 xb = *(const float4*)(xp + kc * 32 + 4);
        float xv[8] = {xa.x, xa.y, xa.z, xa.w, xb.x, xb.y, xb.z, xb.w};
        half8 ah, al;
        #pragma unroll
        for (int j = 0; j < 8; ++j) {
            _Float16 h = (_Float16)xv[j];
            ah[j] = h;
            al[j] = (_Float16)(xv[j] - (float)h);
        }
        const _Float16* sb = &sW[buf][(size_t)lm * 32 + q * 8];
        #pragma unroll
        for (int nt = 0; nt < 17; ++nt) {
            half8 b = *(const half8*)(sb + nt * 512);
            acc[nt] = __builtin_amdgcn_mfma_f32_16x16x32_f16(ah, b, acc[nt], 0, 0, 0);
            acc[nt] = __builtin_amdgcn_mfma_f32_16x16x32_f16(al, b, acc[nt], 0, 0, 0);
        }
        buf ^= 1;
    }

    int rbase = row0 + w * 16 + q * 4;
    #pragma unroll
    for (int r = 0; r < 4; ++r) {
        int row = rbase + r;
        if (row < N_NODES) {
            size_t ro = (size_t)row * 256 + lm;
            #pragma unroll
            for (int nt = 0; nt < 16; ++nt)
                h1h[ro + nt * 16] = (_Float16)acc[nt][r];
            float v = acc[16][r];                  // col 256+lm
            if (lm < 8) als[row * 8 + lm] = v;
            else        ald[row * 8 + (lm - 8)] = v;
        }
    }
}

// ------------- layer 1 aggregation + fused layer-2 GEMV --------------------
// One wave per dst node, ELL list (real edges only; self-loop analytic).
// Main loop: LDS-staged 64-edge chunks, 4-edge inner body (round-4 form:
// 28 VGPR, 4 independent gathers in flight — 8-deep unroll regressed, r5).
// Epilogue: in-register shuffle-tree GEMV with fp32 W2 loads (L1-hot).
__global__ __launch_bounds__(64) void k_agg1(
        const int* __restrict__ cursor, const int* __restrict__ ssrc,
        const _Float16* __restrict__ h1h, const float* __restrict__ als,
        const float* __restrict__ ald, const float* __restrict__ b1,
        const float* __restrict__ W2, const float* __restrict__ as2,
        const float* __restrict__ ad2,
        _Float16* __restrict__ h2h, float* __restrict__ als2,
        float* __restrict__ ald2) {
    __shared__ int   s_lds[64];
    __shared__ float w_lds[64 * 8];
    int l = threadIdx.x;
    int i = blockIdx.x;
    int h = l >> 3;
    float4 ad0  = *(const float4*)(ald + i * 8);
    float4 ad1v = *(const float4*)(ald + i * 8 + 4);

    // ---- analytic self-loop: src = dst = i ----
    float es = als[i * 8 + h] + ald[i * 8 + h];
    es = (es > 0.f) ? es : NEG * es;
    float wself = __expf(es);
    half4_t hvs = *(const half4_t*)(h1h + (size_t)i * 256 + 4 * l);
    float ax = wself * (float)hvs[0];
    float ay = wself * (float)hvs[1];
    float az = wself * (float)hvs[2];
    float aw = wself * (float)hvs[3];
    float dsum = wself;

    int beg = i * ELLW;
    int end = beg + cursor[i];
    for (int c0 = beg; c0 < end; c0 += 64) {
        int nc = min(64, end - c0);
        __syncthreads();
        int jj = (l < nc) ? l : (nc - 1);
        int s = ssrc[c0 + jj];
        s_lds[l] = s;
        float4 s0 = *(const float4*)(als + s * 8);
        float4 s1 = *(const float4*)(als + s * 8 + 4);
        float e0 = s0.x + ad0.x,  e1 = s0.y + ad0.y;
        float e2 = s0.z + ad0.z,  e3 = s0.w + ad0.w;
        float e4 = s1.x + ad1v.x, e5 = s1.y + ad1v.y;
        float e6 = s1.z + ad1v.z, e7 = s1.w + ad1v.w;
        e0 = (e0 > 0.f) ? e0 : NEG * e0;  e1 = (e1 > 0.f) ? e1 : NEG * e1;
        e2 = (e2 > 0.f) ? e2 : NEG * e2;  e3 = (e3 > 0.f) ? e3 : NEG * e3;
        e4 = (e4 > 0.f) ? e4 : NEG * e4;  e5 = (e5 > 0.f) ? e5 : NEG * e5;
        e6 = (e6 > 0.f) ? e6 : NEG * e6;  e7 = (e7 > 0.f) ? e7 : NEG * e7;
        float m = (l < nc) ? 1.f : 0.f;   // zero weight for pad lanes
        float4 w0 = make_float4(m * __expf(e0), m * __expf(e1),
                                m * __expf(e2), m * __expf(e3));
        float4 w1 = make_float4(m * __expf(e4), m * __expf(e5),
                                m * __expf(e6), m * __expf(e7));
        *(float4*)(w_lds + l * 8)     = w0;
        *(float4*)(w_lds + l * 8 + 4) = w1;
        __syncthreads();
        for (int e = 0; e < nc; e += 4) {
            int4 s4 = *(const int4*)(s_lds + e);
            float wa = w_lds[(e + 0) * 8 + h];
            float wb = w_lds[(e + 1) * 8 + h];
            float wc = w_lds[(e + 2) * 8 + h];
            float wd = w_lds[(e + 3) * 8 + h];
            half4_t va = *(const half4_t*)(h1h + (size_t)s4.x * 256 + 4 * l);
            half4_t vb = *(const half4_t*)(h1h + (size_t)s4.y * 256 + 4 * l);
            half4_t vc = *(const half4_t*)(h1h + (size_t)s4.z * 256 + 4 * l);
            half4_t vd = *(const half4_t*)(h1h + (size_t)s4.w * 256 + 4 * l);
            ax += wa * (float)va[0] + wb * (float)vb[0]
                + wc * (float)vc[0] + wd * (float)vd[0];
            ay += wa * (float)va[1] + wb * (float)vb[1]
                + wc * (float)vc[1] + wd * (float)vd[1];
            az += wa * (float)va[2] + wb * (float)vb[2]
                + wc * (float)vc[2] + wd * (float)vd[2];
            aw += wa * (float)va[3] + wb * (float)vb[3]
                + wc * (float)vc[3] + wd * (float)vd[3];
            dsum += wa + wb + wc + wd;
        }
    }
    float dn = 1.0f / (dsum + EPSF);
    float4 b4 = *(const float4*)(b1 + 4 * l);
    float vx = ax * dn + b4.x;
    float vy = ay * dn + b4.y;
    float vz = az * dn + b4.z;
    float vw = aw * dn + b4.w;
    vx = (vx > 0.f) ? vx : (__expf(vx) - 1.f);
    vy = (vy > 0.f) ? vy : (__expf(vy) - 1.f);
    vz = (vz > 0.f) ? vz : (__expf(vz) - 1.f);
    vw = (vw > 0.f) ? vw : (__expf(vw) - 1.f);

    // ---- fused layer-2 GEMV: h2[c] = sum_k hpost[k] * W2[k][c] ----
    // Lane l holds hpost[4l..4l+3]; W2 read as fp32 (L1-hot, epilogue-only).
    float p[16];
    #pragma unroll
    for (int c = 0; c < 16; ++c) p[c] = 0.f;
    float v4a[4] = {vx, vy, vz, vw};
    const float4* w2p = (const float4*)(W2 + (size_t)(4 * l) * 16);
    #pragma unroll
    for (int j = 0; j < 4; ++j) {
        float4 c0 = w2p[j * 4 + 0];
        float4 c1 = w2p[j * 4 + 1];
        float4 c2 = w2p[j * 4 + 2];
        float4 c3 = w2p[j * 4 + 3];
        float vj = v4a[j];
        p[0]  += vj * c0.x;  p[1]  += vj * c0.y;
        p[2]  += vj * c0.z;  p[3]  += vj * c0.w;
        p[4]  += vj * c1.x;  p[5]  += vj * c1.y;
        p[6]  += vj * c1.z;  p[7]  += vj * c1.w;
        p[8]  += vj * c2.x;  p[9]  += vj * c2.y;
        p[10] += vj * c2.z;  p[11] += vj * c2.w;
        p[12] += vj * c3.x;  p[13] += vj * c3.y;
        p[14] += vj * c3.z;  p[15] += vj * c3.w;
    }
    // shuffle-tree: after 4 stages lane l holds partial of channel (l&15)
    bool k1 = (l & 1) != 0;
    float q[8];
    #pragma unroll
    for (int j = 0; j < 8; ++j) {
        float a = p[2 * j], b = p[2 * j + 1];
        float mine = k1 ? b : a;
        float send = k1 ? a : b;
        q[j] = mine + __shfl_xor(send, 1, 64);
    }
    bool k2 = (l & 2) != 0;
    float r4[4];
    #pragma unroll
    for (int j = 0; j < 4; ++j) {
        float a = q[2 * j], b = q[2 * j + 1];
        float mine = k2 ? b : a;
        float send = k2 ? a : b;
        r4[j] = mine + __shfl_xor(send, 2, 64);
    }
    bool k4 = (l & 4) != 0;
    float s2a[2];
    #pragma unroll
    for (int j = 0; j < 2; ++j) {
        float a = r4[2 * j], b = r4[2 * j + 1];
        float mine = k4 ? b : a;
        float send = k4 ? a : b;
        s2a[j] = mine + __shfl_xor(send, 4, 64);
    }
    bool k8 = (l & 8) != 0;
    {
        float a = s2a[0], b = s2a[1];
        float mine = k8 ? b : a;
        float send = k8 ? a : b;
        s2a[0] = mine + __shfl_xor(send, 8, 64);
    }
    float sum = s2a[0];
    sum += __shfl_xor(sum, 16, 64);
    sum += __shfl_xor(sum, 32, 64);        // every lane: h2[l&15]
    int c = l & 15;
    float vs = sum * as2[c];
    float vd = sum * ad2[c];
    #pragma unroll
    for (int m = 1; m < 16; m <<= 1) {
        vs += __shfl_xor(vs, m, 64);
        vd += __shfl_xor(vd, m, 64);
    }
    if (l < 16) h2h[(size_t)i * 16 + l] = (_Float16)sum;
    if (l == 0) { als2[i] = vs; ald2[i] = vd; }
}

// ---------------- layer 2 aggregation -> out (shuffle-only, ELL) -----------
// Self-loop analytic; real edges from ELL list.
__global__ __launch_bounds__(256) void k_agg2(
        const int* __restrict__ cursor, const int* __restrict__ ssrc,
        const _Float16* __restrict__ h2h, const float* __restrict__ als2,
        const float* __restrict__ ald2, const float* __restrict__ b2,
        float* __restrict__ out) {
    int t = threadIdx.x;
    int l = t & 63;
    int i = blockIdx.x * 4 + (t >> 6);
    int c = l & 15, es = l >> 4;
    float adi = ald2[i];

    // analytic self-loop
    float vsl = als2[i] + adi;
    vsl = (vsl > 0.f) ? vsl : NEG * vsl;
    float wself = __expf(vsl);
    float acc  = (es == 0) ? wself * (float)h2h[(size_t)i * C2 + c] : 0.f;
    float dsum = (l == 0) ? wself : 0.f;

    int beg = i * ELLW;
    int end = beg + cursor[i];
    for (int c0 = beg; c0 < end; c0 += 64) {
        int nc = min(64, end - c0);
        int s = 0; float wv = 0.f;
        if (l < nc) {
            s = ssrc[c0 + l];
            float v = als2[s] + adi;
            v = (v > 0.f) ? v : NEG * v;
            wv = __expf(v);
            dsum += wv;
        }
        for (int e0 = 0; e0 < nc; e0 += 4) {     // uniform trip count
            int e = e0 + es;
            int ec = (e < nc) ? e : (nc - 1);
            int se = __shfl(s, ec, 64);
            float we = __shfl(wv, ec, 64);
            if (e < nc) acc += we * (float)h2h[(size_t)se * C2 + c];
        }
    }
    #pragma unroll
    for (int m = 1; m < 64; m <<= 1) dsum += __shfl_xor(dsum, m, 64);
    acc += __shfl_xor(acc, 16, 64);
    acc += __shfl_xor(acc, 32, 64);
    if (l < 16) out[i * C2 + l] = acc / (dsum + EPSF) + b2[l];
}

// ---------------------------------------------------------------------------

extern "C" void kernel_launch(void* const* d_in, const int* in_sizes, int n_in,
                              void* d_out, int out_size, void* d_ws, size_t ws_size,
                              hipStream_t stream) {
    const float* x   = (const float*)d_in[0];
    const int*   ei  = (const int*)d_in[1];
    const float* W1  = (const float*)d_in[2];
    const float* as1 = (const float*)d_in[3];
    const float* ad1 = (const float*)d_in[4];
    const float* b1  = (const float*)d_in[5];
    const float* W2  = (const float*)d_in[6];
    const float* as2 = (const float*)d_in[7];
    const float* ad2 = (const float*)d_in[8];
    const float* b2  = (const float*)d_in[9];
    float* out = (float*)d_out;

    char* ws = (char*)d_ws;
    size_t off = 0;
    auto alloc = [&](size_t bytes) {
        off = (off + 255) & ~(size_t)255;
        void* p = ws + off;
        off += bytes;
        return p;
    };
    _Float16* h1h    = (_Float16*)alloc((size_t)N_NODES * F1 * 2);
    _Float16* h2h    = (_Float16*)alloc((size_t)N_NODES * C2 * 2);
    float* als   = (float*)alloc((size_t)N_NODES * HEADS * 4);
    float* ald   = (float*)alloc((size_t)N_NODES * HEADS * 4);
    float* als2  = (float*)alloc((size_t)N_NODES * 4);
    float* ald2  = (float*)alloc((size_t)N_NODES * 4);
    int*   cursor= (int*)alloc((size_t)N_NODES * 4);
    int*   ssrc  = (int*)alloc((size_t)N_NODES * ELLW * 4);
    _Float16* Wp  = (_Float16*)alloc((size_t)8 * KCHALF * 2);
    (void)ws_size; (void)in_sizes; (void)n_in; (void)out_size;

    k_prep<<<264 + INITB, 256, 0, stream>>>(W1, as1, ad1, Wp, cursor);
    k_gemm1<<<GEMMB + HISTB, 256, 0, stream>>>(x, Wp, h1h, als, ald,
                                               ei, cursor, ssrc);
    k_agg1<<<N_NODES, 64, 0, stream>>>(cursor, ssrc, h1h, als, ald, b1,
                                       W2, as2, ad2, h2h, als2, ald2);
    k_agg2<<<N_NODES / 4, 256, 0, stream>>>(cursor, ssrc, h2h, als2, ald2, b2, out);
}

// Round 7
// 274.274 us; speedup vs baseline: 1.1952x; 1.1645x over previous
//
#include <hip/hip_runtime.h>
#include <hip/hip_bf16.h>
#include <math.h>

#define N_NODES 50000
#define N_EDGES 800000
#define F_IN    256
#define HEADS   8
#define C1      32
#define F1      256   // HEADS*C1
#define C2      16
#define NEG     0.2f
#define EPSF    1e-16f
#define ELLW    96    // ELL width; max degree ~45 for Poisson(16), guarded
#define HISTB   3125  // 800000/256
#define INITB   196   // ceil(50000/256)

// GEMM1 B panel: 272 cols = 256 (W1) + 8 (W1@a_src per head) + 8 (W1@a_dst)
#define NCOLS   272
#define KCHALF  (NCOLS * 32)          // halfs per kc chunk = 8704
#define KCBYTES (KCHALF * 2)          // 17408 B

typedef __attribute__((ext_vector_type(8))) _Float16 half8;
typedef __attribute__((ext_vector_type(4))) _Float16 half4_t;
typedef __attribute__((ext_vector_type(4))) float    floatx4;

// ------------- weight prep + ELL init (merged) -----------------------------
// blocks 0..255   : W1 col -> Wp
// blocks 256..263 : wtS/wtD cols (fused attention coefs)
// block  264      : W2r (fp16 copy of W2, row-major [k][c])
// blocks 265..460 : ELL init: cursor[i]=1, ssrc[i*ELLW]=i (self-loop slot 0)
__global__ void k_prep(const float* __restrict__ W1, const float* __restrict__ W2,
                       const float* __restrict__ as1, const float* __restrict__ ad1,
                       _Float16* __restrict__ Wp, _Float16* __restrict__ W2r,
                       int* __restrict__ cursor, int* __restrict__ ssrc) {
    int b = blockIdx.x;
    int k = threadIdx.x;   // 0..255
    if (b < 256) {
        int n = b;
        float v = W1[k * 256 + n];
        Wp[(k >> 5) * KCHALF + n * 32 + (k & 31)] = (_Float16)v;
    } else if (b < 264) {
        int hd = b - 256;
        float ws = 0.f, wd = 0.f;
        #pragma unroll
        for (int cc = 0; cc < 32; ++cc) {
            float wv = W1[k * 256 + hd * 32 + cc];
            ws += wv * as1[hd * 32 + cc];
            wd += wv * ad1[hd * 32 + cc];
        }
        Wp[(k >> 5) * KCHALF + (256 + hd) * 32 + (k & 31)] = (_Float16)ws;
        Wp[(k >> 5) * KCHALF + (264 + hd) * 32 + (k & 31)] = (_Float16)wd;
    } else if (b == 264) {
        #pragma unroll
        for (int c = 0; c < 16; ++c)
            W2r[k * 16 + c] = (_Float16)W2[k * 16 + c];
    } else {
        int i = (b - 265) * 256 + k;
        if (i < N_NODES) {
            cursor[i] = 1;
            ssrc[(size_t)i * ELLW] = i;
        }
    }
}

// ---------------- ELL scatter: one atomic per edge -------------------------
__global__ void k_scatter(const int* __restrict__ ei, int* __restrict__ cursor,
                          int* __restrict__ ssrc) {
    int i = blockIdx.x * blockDim.x + threadIdx.x;
    if (i >= N_EDGES) return;
    int s = ei[i];
    int d = ei[N_EDGES + i];
    int p = atomicAdd(&cursor[d], 1);
    if (p < ELLW) ssrc[(size_t)d * ELLW + p] = s;
}

// ---------------- layer 1 GEMM via split-fp16 MFMA -------------------------
// [h1 | als | ald] = x @ [W1 | wtS | wtD]. 17 n-tiles of 16.
__global__ __launch_bounds__(256) void k_gemm1(
        const float* __restrict__ x, const _Float16* __restrict__ Wp,
        _Float16* __restrict__ h1h, float* __restrict__ als,
        float* __restrict__ ald) {
    __shared__ _Float16 sW[2][KCHALF];
    int t = threadIdx.x;
    int w = t >> 6, l = t & 63;
    int lm = l & 15, q = l >> 4;
    int row0 = blockIdx.x * 64;
    int arow = row0 + w * 16 + lm;
    int rc = (arow < N_NODES) ? arow : (N_NODES - 1);
    const float* xp = x + (size_t)rc * 256 + q * 8;

    floatx4 acc[17];
    #pragma unroll
    for (int nt = 0; nt < 17; ++nt) acc[nt] = (floatx4){0.f, 0.f, 0.f, 0.f};

    auto stage = [&](int kc, int buf) {
        const float4* g = (const float4*)((const char*)Wp + (size_t)kc * KCBYTES);
        float4* sp = (float4*)&sW[buf][0];
        #pragma unroll
        for (int c = 0; c < 4; ++c) sp[c * 256 + t] = g[c * 256 + t];
        if (t < 64) sp[1024 + t] = g[1024 + t];
    };

    stage(0, 0);
    int buf = 0;
    #pragma unroll 1
    for (int kc = 0; kc < 8; ++kc) {
        __syncthreads();
        if (kc < 7) stage(kc + 1, buf ^ 1);

        float4 xa = *(const float4*)(xp + kc * 32);
        float4 xb = *(const float4*)(xp + kc * 32 + 4);
        float xv[8] = {xa.x, xa.y, xa.z, xa.w, xb.x, xb.y, xb.z, xb.w};
        half8 ah, al;
        #pragma unroll
        for (int j = 0; j < 8; ++j) {
            _Float16 h = (_Float16)xv[j];
            ah[j] = h;
            al[j] = (_Float16)(xv[j] - (float)h);
        }
        const _Float16* sb = &sW[buf][(size_t)lm * 32 + q * 8];
        #pragma unroll
        for (int nt = 0; nt < 17; ++nt) {
            half8 b = *(const half8*)(sb + nt * 512);
            acc[nt] = __builtin_amdgcn_mfma_f32_16x16x32_f16(ah, b, acc[nt], 0, 0, 0);
            acc[nt] = __builtin_amdgcn_mfma_f32_16x16x32_f16(al, b, acc[nt], 0, 0, 0);
        }
        buf ^= 1;
    }

    int rbase = row0 + w * 16 + q * 4;
    #pragma unroll
    for (int r = 0; r < 4; ++r) {
        int row = rbase + r;
        if (row < N_NODES) {
            size_t ro = (size_t)row * 256 + lm;
            #pragma unroll
            for (int nt = 0; nt < 16; ++nt)
                h1h[ro + nt * 16] = (_Float16)acc[nt][r];
            float v = acc[16][r];                  // col 256+lm
            if (lm < 8) als[row * 8 + lm] = v;
            else        ald[row * 8 + (lm - 8)] = v;
        }
    }
}

// ------------- layer 1 aggregation + fused layer-2 GEMV --------------------
// One wave per dst node, ELL list (self-loop in slot 0, r4 semantics).
// NEW main loop: 16 B/lane gathers, two edges per load instruction.
// Lane l: half = l>>5 (edge parity), owns channels cb = 8*(l&31) .. cb+7
// (head h = (l&31)>>2). Inner iteration = 4 paired loads = 8 edges with
// 4 x 16B in flight. Cross-half merge via shfl_xor(32); 9-shuffle remap
// feeds the unchanged r4 epilogue (fp16 W2r shuffle-tree GEMV).
__global__ __launch_bounds__(64, 8) void k_agg1(
        const int* __restrict__ cursor, const int* __restrict__ ssrc,
        const _Float16* __restrict__ h1h, const float* __restrict__ als,
        const float* __restrict__ ald, const float* __restrict__ b1,
        const _Float16* __restrict__ W2r, const float* __restrict__ as2,
        const float* __restrict__ ad2,
        _Float16* __restrict__ h2h, float* __restrict__ als2,
        float* __restrict__ ald2) {
    __shared__ int   s_lds[64];
    __shared__ float w_lds[64 * 8];
    int l = threadIdx.x;
    int i = blockIdx.x;
    int half = l >> 5;            // edge parity within a pair
    int li   = l & 31;
    int cb   = li * 8;            // my channel base (8 channels)
    int h    = li >> 2;           // head of my channels (= cb>>5)
    float4 ad0  = *(const float4*)(ald + i * 8);
    float4 ad1v = *(const float4*)(ald + i * 8 + 4);
    int beg = i * ELLW;
    int end = beg + cursor[i];

    float acc8[8];
    #pragma unroll
    for (int j = 0; j < 8; ++j) acc8[j] = 0.f;
    float dsum = 0.f;

    for (int c0 = beg; c0 < end; c0 += 64) {
        int nc = min(64, end - c0);
        __syncthreads();
        int jj = (l < nc) ? l : (nc - 1);
        int s = ssrc[c0 + jj];
        s_lds[l] = s;
        float4 s0 = *(const float4*)(als + s * 8);
        float4 s1 = *(const float4*)(als + s * 8 + 4);
        float e0 = s0.x + ad0.x,  e1 = s0.y + ad0.y;
        float e2 = s0.z + ad0.z,  e3 = s0.w + ad0.w;
        float e4 = s1.x + ad1v.x, e5 = s1.y + ad1v.y;
        float e6 = s1.z + ad1v.z, e7 = s1.w + ad1v.w;
        e0 = (e0 > 0.f) ? e0 : NEG * e0;  e1 = (e1 > 0.f) ? e1 : NEG * e1;
        e2 = (e2 > 0.f) ? e2 : NEG * e2;  e3 = (e3 > 0.f) ? e3 : NEG * e3;
        e4 = (e4 > 0.f) ? e4 : NEG * e4;  e5 = (e5 > 0.f) ? e5 : NEG * e5;
        e6 = (e6 > 0.f) ? e6 : NEG * e6;  e7 = (e7 > 0.f) ? e7 : NEG * e7;
        float m = (l < nc) ? 1.f : 0.f;   // zero weight for pad lanes
        float4 w0 = make_float4(m * __expf(e0), m * __expf(e1),
                                m * __expf(e2), m * __expf(e3));
        float4 w1 = make_float4(m * __expf(e4), m * __expf(e5),
                                m * __expf(e6), m * __expf(e7));
        *(float4*)(w_lds + l * 8)     = w0;
        *(float4*)(w_lds + l * 8 + 4) = w1;
        __syncthreads();
        // 8 edges per iteration; lane handles edges of its parity.
        // Max slot touched = (last e)+7 <= 63, pads carry w=0 (safe).
        for (int e = 0; e < nc; e += 8) {
            #pragma unroll
            for (int k = 0; k < 4; ++k) {
                int ee = e + 2 * k + half;
                int se = s_lds[ee];
                float we = w_lds[ee * 8 + h];
                half8 hv = *(const half8*)(h1h + (size_t)se * 256 + cb);
                acc8[0] += we * (float)hv[0];
                acc8[1] += we * (float)hv[1];
                acc8[2] += we * (float)hv[2];
                acc8[3] += we * (float)hv[3];
                acc8[4] += we * (float)hv[4];
                acc8[5] += we * (float)hv[5];
                acc8[6] += we * (float)hv[6];
                acc8[7] += we * (float)hv[7];
                dsum += we;
            }
        }
    }
    // merge the two edge-parity halves (lanes l and l^32 share channels)
    #pragma unroll
    for (int j = 0; j < 8; ++j) acc8[j] += __shfl_xor(acc8[j], 32, 64);
    dsum += __shfl_xor(dsum, 32, 64);

    float dn = 1.0f / (dsum + EPSF);
    float4 b4a = *(const float4*)(b1 + cb);
    float4 b4b = *(const float4*)(b1 + cb + 4);
    float bb[8] = {b4a.x, b4a.y, b4a.z, b4a.w, b4b.x, b4b.y, b4b.z, b4b.w};
    float v8[8];
    #pragma unroll
    for (int j = 0; j < 8; ++j) {
        float v = acc8[j] * dn + bb[j];
        v8[j] = (v > 0.f) ? v : (__expf(v) - 1.f);
    }
    // remap: lane l needs channels 4l..4l+3 (live in lane l>>1, lo/hi half)
    float v4a[4];
    #pragma unroll
    for (int j = 0; j < 4; ++j) {
        float lo = __shfl(v8[j],     l >> 1, 64);
        float hi = __shfl(v8[4 + j], l >> 1, 64);
        v4a[j] = (l & 1) ? hi : lo;
    }

    // ---- fused layer-2 GEMV: h2[c] = sum_k hpost[k] * W2[k][c] ----
    float p[16];
    #pragma unroll
    for (int c = 0; c < 16; ++c) p[c] = 0.f;
    const _Float16* w2p = W2r + (size_t)(4 * l) * 16;
    #pragma unroll
    for (int j = 0; j < 4; ++j) {
        half8 lo = *(const half8*)(w2p + j * 16);
        half8 hi = *(const half8*)(w2p + j * 16 + 8);
        #pragma unroll
        for (int c = 0; c < 8; ++c) {
            p[c]     += v4a[j] * (float)lo[c];
            p[c + 8] += v4a[j] * (float)hi[c];
        }
    }
    // shuffle-tree: after 4 stages lane l holds partial of channel (l&15)
    bool k1 = (l & 1) != 0;
    float q[8];
    #pragma unroll
    for (int j = 0; j < 8; ++j) {
        float a = p[2 * j], b = p[2 * j + 1];
        float mine = k1 ? b : a;
        float send = k1 ? a : b;
        q[j] = mine + __shfl_xor(send, 1, 64);
    }
    bool k2 = (l & 2) != 0;
    float r4v[4];
    #pragma unroll
    for (int j = 0; j < 4; ++j) {
        float a = q[2 * j], b = q[2 * j + 1];
        float mine = k2 ? b : a;
        float send = k2 ? a : b;
        r4v[j] = mine + __shfl_xor(send, 2, 64);
    }
    bool k4 = (l & 4) != 0;
    float s2a[2];
    #pragma unroll
    for (int j = 0; j < 2; ++j) {
        float a = r4v[2 * j], b = r4v[2 * j + 1];
        float mine = k4 ? b : a;
        float send = k4 ? a : b;
        s2a[j] = mine + __shfl_xor(send, 4, 64);
    }
    bool k8 = (l & 8) != 0;
    {
        float a = s2a[0], b = s2a[1];
        float mine = k8 ? b : a;
        float send = k8 ? a : b;
        s2a[0] = mine + __shfl_xor(send, 8, 64);
    }
    float sum = s2a[0];
    sum += __shfl_xor(sum, 16, 64);
    sum += __shfl_xor(sum, 32, 64);        // every lane: h2[l&15]
    int c = l & 15;
    float vs = sum * as2[c];
    float vd = sum * ad2[c];
    #pragma unroll
    for (int m2 = 1; m2 < 16; m2 <<= 1) {
        vs += __shfl_xor(vs, m2, 64);
        vd += __shfl_xor(vd, m2, 64);
    }
    if (l < 16) h2h[(size_t)i * 16 + l] = (_Float16)sum;
    if (l == 0) { als2[i] = vs; ald2[i] = vd; }
}

// ---------------- layer 2 aggregation -> out (shuffle-only, ELL) -----------
__global__ __launch_bounds__(256) void k_agg2(
        const int* __restrict__ cursor, const int* __restrict__ ssrc,
        const _Float16* __restrict__ h2h, const float* __restrict__ als2,
        const float* __restrict__ ald2, const float* __restrict__ b2,
        float* __restrict__ out) {
    int t = threadIdx.x;
    int l = t & 63;
    int i = blockIdx.x * 4 + (t >> 6);
    int c = l & 15, es = l >> 4;
    float adi = ald2[i];
    int beg = i * ELLW;
    int end = beg + cursor[i];
    float acc = 0.f, dsum = 0.f;
    for (int c0 = beg; c0 < end; c0 += 64) {
        int nc = min(64, end - c0);
        int s = 0; float wv = 0.f;
        if (l < nc) {
            s = ssrc[c0 + l];
            float v = als2[s] + adi;
            v = (v > 0.f) ? v : NEG * v;
            wv = __expf(v);
            dsum += wv;
        }
        for (int e0 = 0; e0 < nc; e0 += 4) {     // uniform trip count
            int e = e0 + es;
            int ec = (e < nc) ? e : (nc - 1);
            int se = __shfl(s, ec, 64);
            float we = __shfl(wv, ec, 64);
            if (e < nc) acc += we * (float)h2h[(size_t)se * C2 + c];
        }
    }
    #pragma unroll
    for (int m = 1; m < 64; m <<= 1) dsum += __shfl_xor(dsum, m, 64);
    acc += __shfl_xor(acc, 16, 64);
    acc += __shfl_xor(acc, 32, 64);
    if (l < 16) out[i * C2 + l] = acc / (dsum + EPSF) + b2[l];
}

// ---------------------------------------------------------------------------

extern "C" void kernel_launch(void* const* d_in, const int* in_sizes, int n_in,
                              void* d_out, int out_size, void* d_ws, size_t ws_size,
                              hipStream_t stream) {
    const float* x   = (const float*)d_in[0];
    const int*   ei  = (const int*)d_in[1];
    const float* W1  = (const float*)d_in[2];
    const float* as1 = (const float*)d_in[3];
    const float* ad1 = (const float*)d_in[4];
    const float* b1  = (const float*)d_in[5];
    const float* W2  = (const float*)d_in[6];
    const float* as2 = (const float*)d_in[7];
    const float* ad2 = (const float*)d_in[8];
    const float* b2  = (const float*)d_in[9];
    float* out = (float*)d_out;

    char* ws = (char*)d_ws;
    size_t off = 0;
    auto alloc = [&](size_t bytes) {
        off = (off + 255) & ~(size_t)255;
        void* p = ws + off;
        off += bytes;
        return p;
    };
    _Float16* h1h    = (_Float16*)alloc((size_t)N_NODES * F1 * 2);
    _Float16* h2h    = (_Float16*)alloc((size_t)N_NODES * C2 * 2);
    float* als   = (float*)alloc((size_t)N_NODES * HEADS * 4);
    float* ald   = (float*)alloc((size_t)N_NODES * HEADS * 4);
    float* als2  = (float*)alloc((size_t)N_NODES * 4);
    float* ald2  = (float*)alloc((size_t)N_NODES * 4);
    int*   cursor= (int*)alloc((size_t)N_NODES * 4);
    int*   ssrc  = (int*)alloc((size_t)N_NODES * ELLW * 4);
    _Float16* Wp  = (_Float16*)alloc((size_t)8 * KCHALF * 2);
    _Float16* W2r = (_Float16*)alloc((size_t)256 * 16 * 2);
    (void)ws_size; (void)in_sizes; (void)n_in; (void)out_size;

    k_prep<<<265 + INITB, 256, 0, stream>>>(W1, W2, as1, ad1, Wp, W2r, cursor, ssrc);
    k_scatter<<<HISTB, 256, 0, stream>>>(ei, cursor, ssrc);
    k_gemm1<<<(N_NODES + 63) / 64, 256, 0, stream>>>(x, Wp, h1h, als, ald);
    k_agg1<<<N_NODES, 64, 0, stream>>>(cursor, ssrc, h1h, als, ald, b1,
                                       W2r, as2, ad2, h2h, als2, ald2);
    k_agg2<<<N_NODES / 4, 256, 0, stream>>>(cursor, ssrc, h2h, als2, ald2, b2, out);
}

// Round 8
// 257.910 us; speedup vs baseline: 1.2710x; 1.0634x over previous
//
#include <hip/hip_runtime.h>
#include <hip/hip_bf16.h>
#include <math.h>

#define N_NODES 50000
#define N_EDGES 800000
#define F_IN    256
#define HEADS   8
#define C1      32
#define F1      256   // HEADS*C1
#define C2      16
#define NEG     0.2f
#define EPSF    1e-16f
#define ELLW    96    // ELL width; max degree ~45 for Poisson(16), guarded
#define HISTB   3125  // 800000/256
#define INITB   196   // ceil(50000/256)
#define GEMMB   782   // ceil(50000/64)

// GEMM1 B panel: 272 cols = 256 (W1) + 8 (W1@a_src per head) + 8 (W1@a_dst)
#define NCOLS   272
#define KCHALF  (NCOLS * 32)          // halfs per kc chunk = 8704
#define KCBYTES (KCHALF * 2)          // 17408 B

typedef __attribute__((ext_vector_type(8))) _Float16 half8;
typedef __attribute__((ext_vector_type(4))) _Float16 half4_t;
typedef __attribute__((ext_vector_type(4))) float    floatx4;

// ------------- weight prep + ELL init (merged) -----------------------------
// blocks 0..255   : W1 col -> Wp
// blocks 256..263 : wtS/wtD cols (fused attention coefs)
// block  264      : W2r (fp16 copy of W2, row-major [k][c])
// blocks 265..460 : ELL init: cursor[i]=1, ssrc[i*ELLW]=i (self-loop slot 0)
__global__ void k_prep(const float* __restrict__ W1, const float* __restrict__ W2,
                       const float* __restrict__ as1, const float* __restrict__ ad1,
                       _Float16* __restrict__ Wp, _Float16* __restrict__ W2r,
                       int* __restrict__ cursor, int* __restrict__ ssrc) {
    int b = blockIdx.x;
    int k = threadIdx.x;   // 0..255
    if (b < 256) {
        int n = b;
        float v = W1[k * 256 + n];
        Wp[(k >> 5) * KCHALF + n * 32 + (k & 31)] = (_Float16)v;
    } else if (b < 264) {
        int hd = b - 256;
        float ws = 0.f, wd = 0.f;
        #pragma unroll
        for (int cc = 0; cc < 32; ++cc) {
            float wv = W1[k * 256 + hd * 32 + cc];
            ws += wv * as1[hd * 32 + cc];
            wd += wv * ad1[hd * 32 + cc];
        }
        Wp[(k >> 5) * KCHALF + (256 + hd) * 32 + (k & 31)] = (_Float16)ws;
        Wp[(k >> 5) * KCHALF + (264 + hd) * 32 + (k & 31)] = (_Float16)wd;
    } else if (b == 264) {
        #pragma unroll
        for (int c = 0; c < 16; ++c)
            W2r[k * 16 + c] = (_Float16)W2[k * 16 + c];
    } else {
        int i = (b - 265) * 256 + k;
        if (i < N_NODES) {
            cursor[i] = 1;
            ssrc[(size_t)i * ELLW] = i;
        }
    }
}

// -------- layer 1 GEMM via split-fp16 MFMA + ELL scatter (merged grid) -----
// Blocks 0..GEMMB-1: [h1 | als | ald] = x @ [W1 | wtS | wtD], 17 n-tiles.
// Blocks GEMMB..   : edge scatter into ELL (depends only on k_prep, like the
// GEMM; no ordering needed between the two halves -> one dispatch is safe).
__global__ __launch_bounds__(256) void k_gemm1(
        const float* __restrict__ x, const _Float16* __restrict__ Wp,
        _Float16* __restrict__ h1h, float* __restrict__ als,
        float* __restrict__ ald,
        const int* __restrict__ ei, int* __restrict__ cursor,
        int* __restrict__ ssrc) {
    __shared__ _Float16 sW[2][KCHALF];
    if (blockIdx.x >= GEMMB) {
        int i = (blockIdx.x - GEMMB) * 256 + threadIdx.x;
        if (i < N_EDGES) {
            int s = ei[i];
            int d = ei[N_EDGES + i];
            int p = atomicAdd(&cursor[d], 1);
            if (p < ELLW) ssrc[(size_t)d * ELLW + p] = s;
        }
        return;
    }
    int t = threadIdx.x;
    int w = t >> 6, l = t & 63;
    int lm = l & 15, q = l >> 4;
    int row0 = blockIdx.x * 64;
    int arow = row0 + w * 16 + lm;
    int rc = (arow < N_NODES) ? arow : (N_NODES - 1);
    const float* xp = x + (size_t)rc * 256 + q * 8;

    floatx4 acc[17];
    #pragma unroll
    for (int nt = 0; nt < 17; ++nt) acc[nt] = (floatx4){0.f, 0.f, 0.f, 0.f};

    auto stage = [&](int kc, int buf) {
        const float4* g = (const float4*)((const char*)Wp + (size_t)kc * KCBYTES);
        float4* sp = (float4*)&sW[buf][0];
        #pragma unroll
        for (int c = 0; c < 4; ++c) sp[c * 256 + t] = g[c * 256 + t];
        if (t < 64) sp[1024 + t] = g[1024 + t];
    };

    stage(0, 0);
    int buf = 0;
    #pragma unroll 1
    for (int kc = 0; kc < 8; ++kc) {
        __syncthreads();
        if (kc < 7) stage(kc + 1, buf ^ 1);

        float4 xa = *(const float4*)(xp + kc * 32);
        float4 xb = *(const float4*)(xp + kc * 32 + 4);
        float xv[8] = {xa.x, xa.y, xa.z, xa.w, xb.x, xb.y, xb.z, xb.w};
        half8 ah, al;
        #pragma unroll
        for (int j = 0; j < 8; ++j) {
            _Float16 h = (_Float16)xv[j];
            ah[j] = h;
            al[j] = (_Float16)(xv[j] - (float)h);
        }
        const _Float16* sb = &sW[buf][(size_t)lm * 32 + q * 8];
        #pragma unroll
        for (int nt = 0; nt < 17; ++nt) {
            half8 b = *(const half8*)(sb + nt * 512);
            acc[nt] = __builtin_amdgcn_mfma_f32_16x16x32_f16(ah, b, acc[nt], 0, 0, 0);
            acc[nt] = __builtin_amdgcn_mfma_f32_16x16x32_f16(al, b, acc[nt], 0, 0, 0);
        }
        buf ^= 1;
    }

    int rbase = row0 + w * 16 + q * 4;
    #pragma unroll
    for (int r = 0; r < 4; ++r) {
        int row = rbase + r;
        if (row < N_NODES) {
            size_t ro = (size_t)row * 256 + lm;
            #pragma unroll
            for (int nt = 0; nt < 16; ++nt)
                h1h[ro + nt * 16] = (_Float16)acc[nt][r];
            float v = acc[16][r];                  // col 256+lm
            if (lm < 8) als[row * 8 + lm] = v;
            else        ald[row * 8 + (lm - 8)] = v;
        }
    }
}

// ------------- layer 1 aggregation + fused layer-2 GEMV --------------------
// One WAVE per block per dst node. NO __syncthreads: DS ops of a single wave
// are processed in order and lgkmcnt returns in order, so cross-lane LDS RAW
// within the wave is safe; removing the barriers removes the compiler's
// s_waitcnt vmcnt(0) drains, letting h1h gathers stay in flight across chunk
// boundaries and under the epilogue. Main loop: 16 B/lane paired gathers
// (lane l: parity l>>5, channels 8*(l&31)..+7). Epilogue: shuffle-tree GEMV.
__global__ __launch_bounds__(64, 8) void k_agg1(
        const int* __restrict__ cursor, const int* __restrict__ ssrc,
        const _Float16* __restrict__ h1h, const float* __restrict__ als,
        const float* __restrict__ ald, const float* __restrict__ b1,
        const _Float16* __restrict__ W2r, const float* __restrict__ as2,
        const float* __restrict__ ad2,
        _Float16* __restrict__ h2h, float* __restrict__ als2,
        float* __restrict__ ald2) {
    __shared__ int   s_lds[64];
    __shared__ float w_lds[64 * 8];
    int l = threadIdx.x;
    int i = blockIdx.x;
    int half = l >> 5;            // edge parity within a pair
    int li   = l & 31;
    int cb   = li * 8;            // my channel base (8 channels)
    int h    = li >> 2;           // head of my channels (= cb>>5)
    float4 ad0  = *(const float4*)(ald + i * 8);
    float4 ad1v = *(const float4*)(ald + i * 8 + 4);
    int beg = i * ELLW;
    int end = beg + cursor[i];

    float acc8[8];
    #pragma unroll
    for (int j = 0; j < 8; ++j) acc8[j] = 0.f;
    float dsum = 0.f;

    for (int c0 = beg; c0 < end; c0 += 64) {
        int nc = min(64, end - c0);
        int jj = (l < nc) ? l : (nc - 1);
        int s = ssrc[c0 + jj];
        s_lds[l] = s;
        float4 s0 = *(const float4*)(als + s * 8);
        float4 s1 = *(const float4*)(als + s * 8 + 4);
        float e0 = s0.x + ad0.x,  e1 = s0.y + ad0.y;
        float e2 = s0.z + ad0.z,  e3 = s0.w + ad0.w;
        float e4 = s1.x + ad1v.x, e5 = s1.y + ad1v.y;
        float e6 = s1.z + ad1v.z, e7 = s1.w + ad1v.w;
        e0 = (e0 > 0.f) ? e0 : NEG * e0;  e1 = (e1 > 0.f) ? e1 : NEG * e1;
        e2 = (e2 > 0.f) ? e2 : NEG * e2;  e3 = (e3 > 0.f) ? e3 : NEG * e3;
        e4 = (e4 > 0.f) ? e4 : NEG * e4;  e5 = (e5 > 0.f) ? e5 : NEG * e5;
        e6 = (e6 > 0.f) ? e6 : NEG * e6;  e7 = (e7 > 0.f) ? e7 : NEG * e7;
        float m = (l < nc) ? 1.f : 0.f;   // zero weight for pad lanes
        float4 w0 = make_float4(m * __expf(e0), m * __expf(e1),
                                m * __expf(e2), m * __expf(e3));
        float4 w1 = make_float4(m * __expf(e4), m * __expf(e5),
                                m * __expf(e6), m * __expf(e7));
        *(float4*)(w_lds + l * 8)     = w0;
        *(float4*)(w_lds + l * 8 + 4) = w1;
        // (no barrier: same-wave DS ordering + lgkmcnt covers the RAW)
        // 8 edges per iteration; lane handles edges of its parity.
        // Max slot touched <= 63; pads carry w=0 (safe).
        for (int e = 0; e < nc; e += 8) {
            #pragma unroll
            for (int k = 0; k < 4; ++k) {
                int ee = e + 2 * k + half;
                int se = s_lds[ee];
                float we = w_lds[ee * 8 + h];
                half8 hv = *(const half8*)(h1h + (size_t)se * 256 + cb);
                acc8[0] += we * (float)hv[0];
                acc8[1] += we * (float)hv[1];
                acc8[2] += we * (float)hv[2];
                acc8[3] += we * (float)hv[3];
                acc8[4] += we * (float)hv[4];
                acc8[5] += we * (float)hv[5];
                acc8[6] += we * (float)hv[6];
                acc8[7] += we * (float)hv[7];
                dsum += we;
            }
        }
    }
    // merge the two edge-parity halves (lanes l and l^32 share channels)
    #pragma unroll
    for (int j = 0; j < 8; ++j) acc8[j] += __shfl_xor(acc8[j], 32, 64);
    dsum += __shfl_xor(dsum, 32, 64);

    float dn = 1.0f / (dsum + EPSF);
    float4 b4a = *(const float4*)(b1 + cb);
    float4 b4b = *(const float4*)(b1 + cb + 4);
    float bb[8] = {b4a.x, b4a.y, b4a.z, b4a.w, b4b.x, b4b.y, b4b.z, b4b.w};
    float v8[8];
    #pragma unroll
    for (int j = 0; j < 8; ++j) {
        float v = acc8[j] * dn + bb[j];
        v8[j] = (v > 0.f) ? v : (__expf(v) - 1.f);
    }
    // remap: lane l needs channels 4l..4l+3 (live in lane l>>1, lo/hi half)
    float v4a[4];
    #pragma unroll
    for (int j = 0; j < 4; ++j) {
        float lo = __shfl(v8[j],     l >> 1, 64);
        float hi = __shfl(v8[4 + j], l >> 1, 64);
        v4a[j] = (l & 1) ? hi : lo;
    }

    // ---- fused layer-2 GEMV: h2[c] = sum_k hpost[k] * W2[k][c] ----
    float p[16];
    #pragma unroll
    for (int c = 0; c < 16; ++c) p[c] = 0.f;
    const _Float16* w2p = W2r + (size_t)(4 * l) * 16;
    #pragma unroll
    for (int j = 0; j < 4; ++j) {
        half8 lo = *(const half8*)(w2p + j * 16);
        half8 hi = *(const half8*)(w2p + j * 16 + 8);
        #pragma unroll
        for (int c = 0; c < 8; ++c) {
            p[c]     += v4a[j] * (float)lo[c];
            p[c + 8] += v4a[j] * (float)hi[c];
        }
    }
    // shuffle-tree: after 4 stages lane l holds partial of channel (l&15)
    bool k1 = (l & 1) != 0;
    float q[8];
    #pragma unroll
    for (int j = 0; j < 8; ++j) {
        float a = p[2 * j], b = p[2 * j + 1];
        float mine = k1 ? b : a;
        float send = k1 ? a : b;
        q[j] = mine + __shfl_xor(send, 1, 64);
    }
    bool k2 = (l & 2) != 0;
    float r4v[4];
    #pragma unroll
    for (int j = 0; j < 4; ++j) {
        float a = q[2 * j], b = q[2 * j + 1];
        float mine = k2 ? b : a;
        float send = k2 ? a : b;
        r4v[j] = mine + __shfl_xor(send, 2, 64);
    }
    bool k4 = (l & 4) != 0;
    float s2a[2];
    #pragma unroll
    for (int j = 0; j < 2; ++j) {
        float a = r4v[2 * j], b = r4v[2 * j + 1];
        float mine = k4 ? b : a;
        float send = k4 ? a : b;
        s2a[j] = mine + __shfl_xor(send, 4, 64);
    }
    bool k8 = (l & 8) != 0;
    {
        float a = s2a[0], b = s2a[1];
        float mine = k8 ? b : a;
        float send = k8 ? a : b;
        s2a[0] = mine + __shfl_xor(send, 8, 64);
    }
    float sum = s2a[0];
    sum += __shfl_xor(sum, 16, 64);
    sum += __shfl_xor(sum, 32, 64);        // every lane: h2[l&15]
    int c = l & 15;
    float vs = sum * as2[c];
    float vd = sum * ad2[c];
    #pragma unroll
    for (int m2 = 1; m2 < 16; m2 <<= 1) {
        vs += __shfl_xor(vs, m2, 64);
        vd += __shfl_xor(vd, m2, 64);
    }
    if (l < 16) h2h[(size_t)i * 16 + l] = (_Float16)sum;
    if (l == 0) { als2[i] = vs; ald2[i] = vd; }
}

// ---------------- layer 2 aggregation -> out (shuffle-only, ELL) -----------
__global__ __launch_bounds__(256) void k_agg2(
        const int* __restrict__ cursor, const int* __restrict__ ssrc,
        const _Float16* __restrict__ h2h, const float* __restrict__ als2,
        const float* __restrict__ ald2, const float* __restrict__ b2,
        float* __restrict__ out) {
    int t = threadIdx.x;
    int l = t & 63;
    int i = blockIdx.x * 4 + (t >> 6);
    int c = l & 15, es = l >> 4;
    float adi = ald2[i];
    int beg = i * ELLW;
    int end = beg + cursor[i];
    float acc = 0.f, dsum = 0.f;
    for (int c0 = beg; c0 < end; c0 += 64) {
        int nc = min(64, end - c0);
        int s = 0; float wv = 0.f;
        if (l < nc) {
            s = ssrc[c0 + l];
            float v = als2[s] + adi;
            v = (v > 0.f) ? v : NEG * v;
            wv = __expf(v);
            dsum += wv;
        }
        for (int e0 = 0; e0 < nc; e0 += 4) {     // uniform trip count
            int e = e0 + es;
            int ec = (e < nc) ? e : (nc - 1);
            int se = __shfl(s, ec, 64);
            float we = __shfl(wv, ec, 64);
            if (e < nc) acc += we * (float)h2h[(size_t)se * C2 + c];
        }
    }
    #pragma unroll
    for (int m = 1; m < 64; m <<= 1) dsum += __shfl_xor(dsum, m, 64);
    acc += __shfl_xor(acc, 16, 64);
    acc += __shfl_xor(acc, 32, 64);
    if (l < 16) out[i * C2 + l] = acc / (dsum + EPSF) + b2[l];
}

// ---------------------------------------------------------------------------

extern "C" void kernel_launch(void* const* d_in, const int* in_sizes, int n_in,
                              void* d_out, int out_size, void* d_ws, size_t ws_size,
                              hipStream_t stream) {
    const float* x   = (const float*)d_in[0];
    const int*   ei  = (const int*)d_in[1];
    const float* W1  = (const float*)d_in[2];
    const float* as1 = (const float*)d_in[3];
    const float* ad1 = (const float*)d_in[4];
    const float* b1  = (const float*)d_in[5];
    const float* W2  = (const float*)d_in[6];
    const float* as2 = (const float*)d_in[7];
    const float* ad2 = (const float*)d_in[8];
    const float* b2  = (const float*)d_in[9];
    float* out = (float*)d_out;

    char* ws = (char*)d_ws;
    size_t off = 0;
    auto alloc = [&](size_t bytes) {
        off = (off + 255) & ~(size_t)255;
        void* p = ws + off;
        off += bytes;
        return p;
    };
    _Float16* h1h    = (_Float16*)alloc((size_t)N_NODES * F1 * 2);
    _Float16* h2h    = (_Float16*)alloc((size_t)N_NODES * C2 * 2);
    float* als   = (float*)alloc((size_t)N_NODES * HEADS * 4);
    float* ald   = (float*)alloc((size_t)N_NODES * HEADS * 4);
    float* als2  = (float*)alloc((size_t)N_NODES * 4);
    float* ald2  = (float*)alloc((size_t)N_NODES * 4);
    int*   cursor= (int*)alloc((size_t)N_NODES * 4);
    int*   ssrc  = (int*)alloc((size_t)N_NODES * ELLW * 4);
    _Float16* Wp  = (_Float16*)alloc((size_t)8 * KCHALF * 2);
    _Float16* W2r = (_Float16*)alloc((size_t)256 * 16 * 2);
    (void)ws_size; (void)in_sizes; (void)n_in; (void)out_size;

    k_prep<<<265 + INITB, 256, 0, stream>>>(W1, W2, as1, ad1, Wp, W2r, cursor, ssrc);
    k_gemm1<<<GEMMB + HISTB, 256, 0, stream>>>(x, Wp, h1h, als, ald,
                                               ei, cursor, ssrc);
    k_agg1<<<N_NODES, 64, 0, stream>>>(cursor, ssrc, h1h, als, ald, b1,
                                       W2r, as2, ad2, h2h, als2, ald2);
    k_agg2<<<N_NODES / 4, 256, 0, stream>>>(cursor, ssrc, h2h, als2, ald2, b2, out);
}